// Round 4
// baseline (1142.551 us; speedup 1.0000x reference)
//
#include <hip/hip_runtime.h>
#include <hip/hip_fp16.h>
#include <stdint.h>

// ============================================================================
// MEASUREMENT PROBE ROUND: kA body repeated x11, kB body x5 (idempotent —
// every rep recomputes and stores identical values). Purpose: lift both
// kernels above the 43us harness-fill threshold so they appear in rocprof
// top-5 with full counters, and decompose dur_us into per-kernel costs.
// Revert multipliers to 1 next round.
// ============================================================================
#define REP_A 11
#define REP_B 5

#define BATCH  4
#define CCH    128
#define GRID_H 128
#define GRID_W 128
#define NNODE  (GRID_H*GRID_W)   // 16384
#define NHEAD  8
#define DH     16
#define WPAD   68
#define WROWS  144

typedef __attribute__((ext_vector_type(8))) short short8;
typedef __attribute__((ext_vector_type(4))) float f32x4;
typedef __attribute__((ext_vector_type(4))) unsigned u32x4;

__device__ inline unsigned packbf(float a, float b){
    unsigned r;
    asm("v_cvt_pk_bf16_f32 %0, %1, %2" : "=v"(r) : "v"(a), "v"(b));
    return r;
}
__device__ inline unsigned packhf(float a, float b){
    unsigned r;
    asm("v_cvt_pkrtz_f16_f32 %0, %1, %2" : "=v"(r) : "v"(a), "v"(b));
    return r;
}

__global__ void kW(const float* __restrict__ Wl, const float* __restrict__ attS,
                   const float* __restrict__ attD, unsigned* __restrict__ Wb)
{
    __shared__ float Wa[8][16];
    const int t = threadIdx.x;
    const int cbase = blockIdx.x * 8;
    if (t < 128){
        int cl = t >> 4, j = t & 15;
        const float* av = (j < 8 ? attS + j*DH : attD + (j-8)*DH);
        const float* wr = Wl + (size_t)(cbase + cl)*CCH + (j & 7)*DH;
        float s = 0.f;
        #pragma unroll
        for (int d = 0; d < DH; ++d) s += wr[d]*av[d];
        Wa[cl][j] = s;
    }
    __syncthreads();
    for (int it = 0; it < 3; ++it){
        int flat = it*256 + t;
        if (flat < 576){
            int k2l = flat / 144, co = flat % 144;
            int k2 = blockIdx.x*4 + k2l;
            float w0, w1;
            if (co < CCH){
                w0 = Wl[(size_t)(2*k2)*CCH + co];
                w1 = Wl[(size_t)(2*k2+1)*CCH + co];
            } else {
                w0 = Wa[2*k2l][co-CCH];
                w1 = Wa[2*k2l+1][co-CCH];
            }
            Wb[co*WPAD + k2] = packbf(w0, w1);
        }
    }
}

__global__ __launch_bounds__(256, 3) void kA(
    const float* __restrict__ x, const unsigned* __restrict__ Wbg,
    __half* __restrict__ xpb, float* __restrict__ scS, float* __restrict__ scD)
{
    __shared__ __align__(16) unsigned WbL[WROWS*WPAD];

    const int t  = threadIdx.x;
    const int b  = blockIdx.y;
    const int bx = blockIdx.x;
    const int row = (bx & 7)*16 + (bx >> 3);
    const int n0  = row * GRID_W;

    #pragma unroll
    for (int it = 0; it < 10; ++it){
        int f4 = it*256 + t;
        if (f4 < (WROWS*WPAD)/4)
            *(u32x4*)(&WbL[f4*4]) = *(const u32x4*)(Wbg + (size_t)f4*4);
    }
    __syncthreads();

    const int w = t >> 6, lane = t & 63;
    const int col = lane & 15, q = lane >> 4;
    const float* xb = x + (size_t)b*CCH*NNODE;
    const int nA = n0 + (2*w+0)*16 + col;
    const int nB = n0 + (2*w+1)*16 + col;

    union U { u32x4 u; short8 s; };

    #pragma unroll 1
    for (int rep = 0; rep < REP_A; ++rep){
        asm volatile("" ::: "memory");     // force reloads each rep

        f32x4 acc[2][9];
        #pragma unroll
        for (int mi = 0; mi < 2; ++mi)
            #pragma unroll
            for (int ct = 0; ct < 9; ++ct) acc[mi][ct] = (f32x4)(0.f);

        float xrA[8], xrB[8], x2A[8], x2B[8];
        #pragma unroll
        for (int j = 0; j < 8; ++j){
            const size_t co = (size_t)(q*8 + j)*NNODE;
            xrA[j] = xb[co + nA];
            xrB[j] = xb[co + nB];
        }

        #pragma unroll
        for (int kc = 0; kc < 4; ++kc){
            if (kc < 3){
                #pragma unroll
                for (int j = 0; j < 8; ++j){
                    const size_t co = (size_t)((kc+1)*32 + q*8 + j)*NNODE;
                    x2A[j] = xb[co + nA];
                    x2B[j] = xb[co + nB];
                }
            }
            U fa0, fa1;
            #pragma unroll
            for (int i = 0; i < 4; ++i){
                fa0.u[i] = packbf(xrA[2*i], xrA[2*i+1]);
                fa1.u[i] = packbf(xrB[2*i], xrB[2*i+1]);
            }
            const int kof = kc*16 + q*4;
            #pragma unroll
            for (int ct = 0; ct < 9; ++ct){
                U fb; fb.u = *(const u32x4*)(&WbL[(ct*16+col)*WPAD + kof]);
                acc[0][ct] = __builtin_amdgcn_mfma_f32_16x16x32_bf16(fa0.s, fb.s, acc[0][ct], 0, 0, 0);
                acc[1][ct] = __builtin_amdgcn_mfma_f32_16x16x32_bf16(fa1.s, fb.s, acc[1][ct], 0, 0, 0);
            }
            #pragma unroll
            for (int j = 0; j < 8; ++j){ xrA[j] = x2A[j]; xrB[j] = x2B[j]; }
        }

        __half* xr = xpb + (size_t)b*NNODE*CCH;
        float*  sS = scS + (size_t)b*NNODE*NHEAD;
        float*  sD = scD + (size_t)b*NNODE*NHEAD;
        #pragma unroll
        for (int mi = 0; mi < 2; ++mi){
            #pragma unroll
            for (int r = 0; r < 4; ++r){
                const int n = n0 + (2*w+mi)*16 + q*4 + r;
                #pragma unroll
                for (int ct = 0; ct < 8; ++ct)
                    xr[(size_t)n*CCH + ct*16 + col] = __float2half(acc[mi][ct][r]);
                const float v = acc[mi][8][r];
                if (col < 8) sS[(size_t)n*NHEAD + col]     = v;
                else         sD[(size_t)n*NHEAD + col - 8] = v;
            }
        }
    }
}

__device__ inline void kb_issue(int n, const float* __restrict__ scSb,
                                const float* __restrict__ scDb,
                                const uint2* __restrict__ xvb, int h, int l2,
                                int* vm, float aS[9], float* aD, uint2 xv[9])
{
    const int rr = n >> 7, cc = n & 127;
    const bool vU = rr > 0, vD = rr < GRID_H-1, vL = cc > 0, vR = cc < GRID_W-1;
    int m = 0;
    #pragma unroll
    for (int e = 0; e < 9; ++e){
        const int dr = e/3 - 1, dc = e%3 - 1;
        const bool vr_ = (dr < 0) ? vU : (dr > 0 ? vD : true);
        const bool vc_ = (dc < 0) ? vL : (dc > 0 ? vR : true);
        const bool v = vr_ && vc_;
        const int src = v ? (n + dr*GRID_W + dc) : n;
        m |= ((int)v) << e;
        aS[e] = scSb[src*NHEAD + h];
        xv[e] = xvb[(size_t)src*32 + l2];
    }
    *aD = scDb[n*NHEAD + h];
    *vm = m;
}

__global__ __launch_bounds__(256, 4) void kB(
    const __half* __restrict__ xpb, const float* __restrict__ scS,
    const float* __restrict__ scD,
    const float* __restrict__ bias, const float* __restrict__ gamma,
    const float* __restrict__ beta, float* __restrict__ out)
{
    __shared__ float outT[CCH][65];
    const int t = threadIdx.x, w = t >> 6, lane = t & 63;
    const int h2 = lane >> 5, l2 = lane & 31;
    const int b  = blockIdx.y;
    const int bx = blockIdx.x;
    const int xcd = bx & 7, rest = bx >> 3;
    const int hlf = rest & 1, rowin = rest >> 1;
    const int n0  = (xcd*16 + rowin)*GRID_W + hlf*64;

    const uint2* xvb  = (const uint2*)(xpb + (size_t)b*NNODE*CCH);
    const float* scSb = scS + (size_t)b*NNODE*NHEAD;
    const float* scDb = scD + (size_t)b*NNODE*NHEAD;
    const int h = l2 >> 2;
    const f32x4 bi = *(const f32x4*)(bias  + 4*l2);
    const f32x4 ga = *(const f32x4*)(gamma + 4*l2);
    const f32x4 be = *(const f32x4*)(beta  + 4*l2);

    float aSP[2][9]; uint2 xvP[2][9]; float aDP[2]; int vmP[2];

    #define NODE(i) (n0 + w*16 + 2*(i) + h2)

    #pragma unroll 1
    for (int rep = 0; rep < REP_B; ++rep){
        asm volatile("" ::: "memory");     // force reloads each rep

        kb_issue(NODE(0), scSb, scDb, xvb, h, l2, &vmP[0], aSP[0], &aDP[0], xvP[0]);

        #pragma unroll
        for (int ii = 0; ii < 4; ++ii){
            #pragma unroll
            for (int ph = 0; ph < 2; ++ph){
                const int i = 2*ii + ph;
                const int cur = i & 1;
                if (i + 1 < 8)
                    kb_issue(NODE(i+1), scSb, scDb, xvb, h, l2,
                             &vmP[cur^1], aSP[cur^1], &aDP[cur^1], xvP[cur^1]);

                const int vm = vmP[cur];
                const float* aS = aSP[cur];
                const uint2*  xv = xvP[cur];
                const float ad = aDP[cur];
                const int nl = w*16 + 2*i + h2;

                float s[9], mx = -1e30f;
                #pragma unroll
                for (int e = 0; e < 9; ++e){
                    float sv = aS[e] + ad;
                    sv = fmaxf(sv, 0.2f*sv);
                    s[e] = ((vm >> e) & 1) ? sv : -1e30f;
                    mx = fmaxf(mx, s[e]);
                }
                float wt[9], den = 0.f;
                #pragma unroll
                for (int e = 0; e < 9; ++e){
                    float ex = __expf(s[e] - mx);
                    ex = ((vm >> e) & 1) ? ex : 0.f;
                    wt[e] = ex; den += ex;
                }
                den += wt[4];
                const float inv = __builtin_amdgcn_rcpf(den);

                union HU { unsigned u; __half2 h; };
                HU a01, a23; a01.u = 0u; a23.u = 0u;
                #pragma unroll
                for (int e = 0; e < 9; ++e){
                    float f = wt[e] * inv;
                    if (e == 4) f += f;
                    HU hf; hf.u = packhf(f, f);
                    HU lo; lo.u = xv[e].x;
                    HU hi; hi.u = xv[e].y;
                    a01.h = __hfma2(hf.h, lo.h, a01.h);
                    a23.h = __hfma2(hf.h, hi.h, a23.h);
                }
                const float a0 = __low2float(a01.h), a1 = __high2float(a01.h);
                const float a2 = __low2float(a23.h), a3 = __high2float(a23.h);

                float o0 = a0 + bi[0], o1 = a1 + bi[1], o2 = a2 + bi[2], o3 = a3 + bi[3];
                o0 = o0 > 0.f ? o0 : __expf(o0) - 1.f;
                o1 = o1 > 0.f ? o1 : __expf(o1) - 1.f;
                o2 = o2 > 0.f ? o2 : __expf(o2) - 1.f;
                o3 = o3 > 0.f ? o3 : __expf(o3) - 1.f;

                float sm = (o0 + o1) + (o2 + o3);
                float sq = o0*o0 + o1*o1 + o2*o2 + o3*o3;
                #pragma unroll
                for (int off = 1; off <= 16; off <<= 1){
                    sm += __shfl_xor(sm, off, 64);
                    sq += __shfl_xor(sq, off, 64);
                }
                const float mu  = sm * (1.f/128.f);
                float var = sq * (1.f/128.f) - mu*mu;
                var = var < 0.f ? 0.f : var;
                const float rstd = __builtin_amdgcn_rsqf(var + 1e-5f);
                outT[4*l2+0][nl] = (o0 - mu)*rstd*ga[0] + be[0];
                outT[4*l2+1][nl] = (o1 - mu)*rstd*ga[1] + be[1];
                outT[4*l2+2][nl] = (o2 - mu)*rstd*ga[2] + be[2];
                outT[4*l2+3][nl] = (o3 - mu)*rstd*ga[3] + be[3];
            }
        }
        __syncthreads();

        float* ob = out + (size_t)b*CCH*NNODE + n0;
        #pragma unroll
        for (int it = 0; it < 32; ++it){
            int c = it*4 + w;
            ob[(size_t)c*NNODE + lane] = outT[c][lane];
        }
        __syncthreads();                   // outT reuse across reps
    }
    #undef NODE
}

extern "C" void kernel_launch(void* const* d_in, const int* in_sizes, int n_in,
                              void* d_out, int out_size, void* d_ws, size_t ws_size,
                              hipStream_t stream)
{
    const float* x    = (const float*)d_in[0];
    const float* Wl   = (const float*)d_in[1];
    const float* attS = (const float*)d_in[2];
    const float* attD = (const float*)d_in[3];
    const float* bias = (const float*)d_in[4];
    const float* gamma= (const float*)d_in[5];
    const float* beta = (const float*)d_in[6];
    float* out = (float*)d_out;

    __half* xpb = (__half*)d_ws;                                        // B*N*128 f16
    float*  scS = (float*)((char*)d_ws + (size_t)BATCH*NNODE*CCH*2);    // B*N*8 f32
    float*  scD = scS + (size_t)BATCH*NNODE*NHEAD;                      // B*N*8 f32
    unsigned* Wb = (unsigned*)(scD + (size_t)BATCH*NNODE*NHEAD);        // 144*68 u32

    kW<<<dim3(16),               256, 0, stream>>>(Wl, attS, attD, Wb);
    kA<<<dim3(NNODE/128, BATCH), 256, 0, stream>>>(x, Wb, xpb, scS, scD);
    kB<<<dim3(NNODE/64,  BATCH), 256, 0, stream>>>(xpb, scS, scD, bias, gamma, beta, out);
}

// Round 5
// 119.590 us; speedup vs baseline: 9.5539x; 9.5539x over previous
//
#include <hip/hip_runtime.h>
#include <hip/hip_fp16.h>
#include <stdint.h>

#define BATCH  4
#define CCH    128
#define GRID_H 128
#define GRID_W 128
#define NNODE  (GRID_H*GRID_W)   // 16384
#define NHEAD  8
#define DH     16
#define WPAD   68
#define WROWS  144

typedef __attribute__((ext_vector_type(8))) short short8;
typedef __attribute__((ext_vector_type(4))) float f32x4;
typedef __attribute__((ext_vector_type(4))) unsigned u32x4;

__device__ inline unsigned packbf(float a, float b){
    unsigned r;
    asm("v_cvt_pk_bf16_f32 %0, %1, %2" : "=v"(r) : "v"(a), "v"(b));
    return r;
}
__device__ inline unsigned packhf(float a, float b){
    unsigned r;
    asm("v_cvt_pkrtz_f16_f32 %0, %1, %2" : "=v"(r) : "v"(a), "v"(b));
    return r;
}

__global__ void kW(const float* __restrict__ Wl, const float* __restrict__ attS,
                   const float* __restrict__ attD, unsigned* __restrict__ Wb)
{
    __shared__ float Wa[8][16];
    const int t = threadIdx.x;
    const int cbase = blockIdx.x * 8;
    if (t < 128){
        int cl = t >> 4, j = t & 15;
        const float* av = (j < 8 ? attS + j*DH : attD + (j-8)*DH);
        const float* wr = Wl + (size_t)(cbase + cl)*CCH + (j & 7)*DH;
        float s = 0.f;
        #pragma unroll
        for (int d = 0; d < DH; ++d) s += wr[d]*av[d];
        Wa[cl][j] = s;
    }
    __syncthreads();
    for (int it = 0; it < 3; ++it){
        int flat = it*256 + t;
        if (flat < 576){
            int k2l = flat / 144, co = flat % 144;
            int k2 = blockIdx.x*4 + k2l;
            float w0, w1;
            if (co < CCH){
                w0 = Wl[(size_t)(2*k2)*CCH + co];
                w1 = Wl[(size_t)(2*k2+1)*CCH + co];
            } else {
                w0 = Wa[2*k2l][co-CCH];
                w1 = Wa[2*k2l+1][co-CCH];
            }
            Wb[co*WPAD + k2] = packbf(w0, w1);
        }
    }
}

// ---------------------------------------------------------------------------
// kA: unchanged structure; x loads now NONTEMPORAL (read-once stream, 33.5 MB)
// so they don't evict the xp/score lines kB is about to consume from L2.
// ---------------------------------------------------------------------------
__global__ __launch_bounds__(256, 3) void kA(
    const float* __restrict__ x, const unsigned* __restrict__ Wbg,
    __half* __restrict__ xpb, float* __restrict__ scS, float* __restrict__ scD)
{
    __shared__ __align__(16) unsigned WbL[WROWS*WPAD];

    const int t  = threadIdx.x;
    const int b  = blockIdx.y;
    const int bx = blockIdx.x;
    const int row = (bx & 7)*16 + (bx >> 3);
    const int n0  = row * GRID_W;

    #pragma unroll
    for (int it = 0; it < 10; ++it){
        int f4 = it*256 + t;
        if (f4 < (WROWS*WPAD)/4)
            *(u32x4*)(&WbL[f4*4]) = *(const u32x4*)(Wbg + (size_t)f4*4);
    }
    __syncthreads();

    const int w = t >> 6, lane = t & 63;
    const int col = lane & 15, q = lane >> 4;
    const float* xb = x + (size_t)b*CCH*NNODE;
    const int nA = n0 + (2*w+0)*16 + col;
    const int nB = n0 + (2*w+1)*16 + col;

    f32x4 acc[2][9];
    #pragma unroll
    for (int mi = 0; mi < 2; ++mi)
        #pragma unroll
        for (int ct = 0; ct < 9; ++ct) acc[mi][ct] = (f32x4)(0.f);

    float xrA[8], xrB[8], x2A[8], x2B[8];
    #pragma unroll
    for (int j = 0; j < 8; ++j){
        const size_t co = (size_t)(q*8 + j)*NNODE;
        xrA[j] = __builtin_nontemporal_load(&xb[co + nA]);
        xrB[j] = __builtin_nontemporal_load(&xb[co + nB]);
    }

    union U { u32x4 u; short8 s; };
    #pragma unroll
    for (int kc = 0; kc < 4; ++kc){
        if (kc < 3){
            #pragma unroll
            for (int j = 0; j < 8; ++j){
                const size_t co = (size_t)((kc+1)*32 + q*8 + j)*NNODE;
                x2A[j] = __builtin_nontemporal_load(&xb[co + nA]);
                x2B[j] = __builtin_nontemporal_load(&xb[co + nB]);
            }
        }
        U fa0, fa1;
        #pragma unroll
        for (int i = 0; i < 4; ++i){
            fa0.u[i] = packbf(xrA[2*i], xrA[2*i+1]);
            fa1.u[i] = packbf(xrB[2*i], xrB[2*i+1]);
        }
        const int kof = kc*16 + q*4;
        #pragma unroll
        for (int ct = 0; ct < 9; ++ct){
            U fb; fb.u = *(const u32x4*)(&WbL[(ct*16+col)*WPAD + kof]);
            acc[0][ct] = __builtin_amdgcn_mfma_f32_16x16x32_bf16(fa0.s, fb.s, acc[0][ct], 0, 0, 0);
            acc[1][ct] = __builtin_amdgcn_mfma_f32_16x16x32_bf16(fa1.s, fb.s, acc[1][ct], 0, 0, 0);
        }
        #pragma unroll
        for (int j = 0; j < 8; ++j){ xrA[j] = x2A[j]; xrB[j] = x2B[j]; }
    }

    __half* xr = xpb + (size_t)b*NNODE*CCH;
    float*  sS = scS + (size_t)b*NNODE*NHEAD;
    float*  sD = scD + (size_t)b*NNODE*NHEAD;
    #pragma unroll
    for (int mi = 0; mi < 2; ++mi){
        #pragma unroll
        for (int r = 0; r < 4; ++r){
            const int n = n0 + (2*w+mi)*16 + q*4 + r;
            #pragma unroll
            for (int ct = 0; ct < 8; ++ct)
                xr[(size_t)n*CCH + ct*16 + col] = __float2half(acc[mi][ct][r]);
            const float v = acc[mi][8][r];
            if (col < 8) sS[(size_t)n*NHEAD + col]     = v;
            else         sD[(size_t)n*NHEAD + col - 8] = v;
        }
    }
}

// ---------------------------------------------------------------------------
// kB: 64 nodes/block as a 2-row x 32-col tile (halo footprint 4x34 = 2.1x
// work, was 3x66 = 3.1x). out stores NONTEMPORAL (never re-read; stop L2
// thrash of the xp band). XCD swizzle keeps rows [16x,16x+16) on XCD x,
// matching kA placement; per-XCD band now fits L2 with out excluded.
// ---------------------------------------------------------------------------
__device__ inline void kb_issue(int n, const float* __restrict__ scSb,
                                const float* __restrict__ scDb,
                                const uint2* __restrict__ xvb, int h, int l2,
                                int* vm, float aS[9], float* aD, uint2 xv[9])
{
    const int rr = n >> 7, cc = n & 127;
    const bool vU = rr > 0, vD = rr < GRID_H-1, vL = cc > 0, vR = cc < GRID_W-1;
    int m = 0;
    #pragma unroll
    for (int e = 0; e < 9; ++e){
        const int dr = e/3 - 1, dc = e%3 - 1;
        const bool vr_ = (dr < 0) ? vU : (dr > 0 ? vD : true);
        const bool vc_ = (dc < 0) ? vL : (dc > 0 ? vR : true);
        const bool v = vr_ && vc_;
        const int src = v ? (n + dr*GRID_W + dc) : n;
        m |= ((int)v) << e;
        aS[e] = scSb[src*NHEAD + h];
        xv[e] = xvb[(size_t)src*32 + l2];
    }
    *aD = scDb[n*NHEAD + h];
    *vm = m;
}

__global__ __launch_bounds__(256, 4) void kB(
    const __half* __restrict__ xpb, const float* __restrict__ scS,
    const float* __restrict__ scD,
    const float* __restrict__ bias, const float* __restrict__ gamma,
    const float* __restrict__ beta, float* __restrict__ out)
{
    __shared__ float outT[CCH][65];
    const int t = threadIdx.x, w = t >> 6, lane = t & 63;
    const int h2 = lane >> 5, l2 = lane & 31;
    const int b  = blockIdx.y;
    const int bx = blockIdx.x;
    // bijective: bx = {cq:2 | mid:3 | xcd:3}; XCD x -> row-pairs [8x, 8x+8)
    const int xcd = bx & 7, mid = (bx >> 3) & 7, cq = bx >> 6;
    const int r0 = (xcd*8 + mid)*2, c0 = cq*32;
    const int n0 = r0*GRID_W + c0;

    const uint2* xvb  = (const uint2*)(xpb + (size_t)b*NNODE*CCH);
    const float* scSb = scS + (size_t)b*NNODE*NHEAD;
    const float* scDb = scD + (size_t)b*NNODE*NHEAD;
    const int h = l2 >> 2;
    const f32x4 bi = *(const f32x4*)(bias  + 4*l2);
    const f32x4 ga = *(const f32x4*)(gamma + 4*l2);
    const f32x4 be = *(const f32x4*)(beta  + 4*l2);

    float aSP[2][9]; uint2 xvP[2][9]; float aDP[2]; int vmP[2];

    // node-local index nl = w*16+2i+h2 in 0..63; tile decode: row-part nl>>5, col nl&31
    #define NODE(i) ({ const int nl_ = w*16 + 2*(i) + h2; \
                       n0 + (nl_ >> 5)*GRID_W + (nl_ & 31); })

    kb_issue(NODE(0), scSb, scDb, xvb, h, l2, &vmP[0], aSP[0], &aDP[0], xvP[0]);

    #pragma unroll
    for (int ii = 0; ii < 4; ++ii){
        #pragma unroll
        for (int ph = 0; ph < 2; ++ph){
            const int i = 2*ii + ph;
            const int cur = i & 1;
            if (i + 1 < 8)
                kb_issue(NODE(i+1), scSb, scDb, xvb, h, l2,
                         &vmP[cur^1], aSP[cur^1], &aDP[cur^1], xvP[cur^1]);

            const int vm = vmP[cur];
            const float* aS = aSP[cur];
            const uint2*  xv = xvP[cur];
            const float ad = aDP[cur];
            const int nl = w*16 + 2*i + h2;

            float s[9], mx = -1e30f;
            #pragma unroll
            for (int e = 0; e < 9; ++e){
                float sv = aS[e] + ad;
                sv = fmaxf(sv, 0.2f*sv);
                s[e] = ((vm >> e) & 1) ? sv : -1e30f;
                mx = fmaxf(mx, s[e]);
            }
            float wt[9], den = 0.f;
            #pragma unroll
            for (int e = 0; e < 9; ++e){
                float ex = __expf(s[e] - mx);
                ex = ((vm >> e) & 1) ? ex : 0.f;
                wt[e] = ex; den += ex;
            }
            den += wt[4];
            const float inv = __builtin_amdgcn_rcpf(den);

            union HU { unsigned u; __half2 h; };
            HU a01, a23; a01.u = 0u; a23.u = 0u;
            #pragma unroll
            for (int e = 0; e < 9; ++e){
                float f = wt[e] * inv;
                if (e == 4) f += f;
                HU hf; hf.u = packhf(f, f);
                HU lo; lo.u = xv[e].x;
                HU hi; hi.u = xv[e].y;
                a01.h = __hfma2(hf.h, lo.h, a01.h);
                a23.h = __hfma2(hf.h, hi.h, a23.h);
            }
            const float a0 = __low2float(a01.h), a1 = __high2float(a01.h);
            const float a2 = __low2float(a23.h), a3 = __high2float(a23.h);

            float o0 = a0 + bi[0], o1 = a1 + bi[1], o2 = a2 + bi[2], o3 = a3 + bi[3];
            o0 = o0 > 0.f ? o0 : __expf(o0) - 1.f;
            o1 = o1 > 0.f ? o1 : __expf(o1) - 1.f;
            o2 = o2 > 0.f ? o2 : __expf(o2) - 1.f;
            o3 = o3 > 0.f ? o3 : __expf(o3) - 1.f;

            float sm = (o0 + o1) + (o2 + o3);
            float sq = o0*o0 + o1*o1 + o2*o2 + o3*o3;
            #pragma unroll
            for (int off = 1; off <= 16; off <<= 1){
                sm += __shfl_xor(sm, off, 64);
                sq += __shfl_xor(sq, off, 64);
            }
            const float mu  = sm * (1.f/128.f);
            float var = sq * (1.f/128.f) - mu*mu;
            var = var < 0.f ? 0.f : var;
            const float rstd = __builtin_amdgcn_rsqf(var + 1e-5f);
            outT[4*l2+0][nl] = (o0 - mu)*rstd*ga[0] + be[0];
            outT[4*l2+1][nl] = (o1 - mu)*rstd*ga[1] + be[1];
            outT[4*l2+2][nl] = (o2 - mu)*rstd*ga[2] + be[2];
            outT[4*l2+3][nl] = (o3 - mu)*rstd*ga[3] + be[3];
        }
    }
    #undef NODE
    __syncthreads();

    float* ob = out + (size_t)b*CCH*NNODE + n0;
    const int poff = (lane >> 5)*GRID_W + (lane & 31);   // 2x32 tile decode
    #pragma unroll
    for (int it = 0; it < 32; ++it){
        int c = it*4 + w;
        __builtin_nontemporal_store(outT[c][lane], &ob[(size_t)c*NNODE + poff]);
    }
}

extern "C" void kernel_launch(void* const* d_in, const int* in_sizes, int n_in,
                              void* d_out, int out_size, void* d_ws, size_t ws_size,
                              hipStream_t stream)
{
    const float* x    = (const float*)d_in[0];
    const float* Wl   = (const float*)d_in[1];
    const float* attS = (const float*)d_in[2];
    const float* attD = (const float*)d_in[3];
    const float* bias = (const float*)d_in[4];
    const float* gamma= (const float*)d_in[5];
    const float* beta = (const float*)d_in[6];
    float* out = (float*)d_out;

    __half* xpb = (__half*)d_ws;                                        // B*N*128 f16
    float*  scS = (float*)((char*)d_ws + (size_t)BATCH*NNODE*CCH*2);    // B*N*8 f32
    float*  scD = scS + (size_t)BATCH*NNODE*NHEAD;                      // B*N*8 f32
    unsigned* Wb = (unsigned*)(scD + (size_t)BATCH*NNODE*NHEAD);        // 144*68 u32

    kW<<<dim3(16),               256, 0, stream>>>(Wl, attS, attD, Wb);
    kA<<<dim3(NNODE/128, BATCH), 256, 0, stream>>>(x, Wb, xpb, scS, scD);
    kB<<<dim3(NNODE/64,  BATCH), 256, 0, stream>>>(xpb, scS, scD, bias, gamma, beta, out);
}